// Round 9
// baseline (305.594 us; speedup 1.0000x reference)
//
#include <hip/hip_runtime.h>
#include <math.h>

// Problem sizes (fixed by reference)
#define Bq 1024
#define Nn 128
#define Mm 8192
#define Ss 256

typedef _Float16 f16;
typedef _Float16 f16x8 __attribute__((ext_vector_type(8)));
typedef float f32x4 __attribute__((ext_vector_type(4)));
typedef float f32x16 __attribute__((ext_vector_type(16)));

#define PI_F 3.14159265358979323846f
#define INV_SQRT_PI 0.5641895835477563f
#define TINY_F 1.17549435e-38f
#define EPS_TOTAL 1e-3f
#define WSC 1024.0f   // w scaling so f16 w stays out of subnormals

// async global->LDS copy, 16B per lane; LDS dest = wave-uniform base + lane*16
#define GLOAD16(g, l) \
    __builtin_amdgcn_global_load_lds((const __attribute__((address_space(1))) void*)(g), \
                                     (__attribute__((address_space(3))) void*)(l), 16, 0, 0)

// ---------------- prep A: |z|^2, 1/|d|, pack Az=[zr|zi], Au=[ur|ui] ----------------
__global__ void cpsf_prep_a(const float* __restrict__ z_re, const float* __restrict__ z_im,
                            const float* __restrict__ d_re, const float* __restrict__ d_im,
                            float* __restrict__ z2, f16* __restrict__ Az, f16* __restrict__ Au)
{
    const int b = blockIdx.x * 4 + (threadIdx.x >> 6);
    const int l = threadIdx.x & 63;
    const int o = b * Nn;
    float dr0 = d_re[o + l], dr1 = d_re[o + l + 64];
    float di0 = d_im[o + l], di1 = d_im[o + l + 64];
    float zr0 = z_re[o + l], zr1 = z_re[o + l + 64];
    float zi0 = z_im[o + l], zi1 = z_im[o + l + 64];
    float sd = dr0*dr0 + di0*di0 + dr1*dr1 + di1*di1;
    float sz = zr0*zr0 + zi0*zi0 + zr1*zr1 + zi1*zi1;
#pragma unroll
    for (int off = 1; off < 64; off <<= 1) {
        sd += __shfl_xor(sd, off);
        sz += __shfl_xor(sz, off);
    }
    float nd = sqrtf(sd);
    nd = (nd == 0.0f) ? 1.0f : nd;
    float inv = 1.0f / nd;
    if (l == 0) z2[b] = sz;
    const int o2 = b * 256;
    Az[o2 + l]       = (f16)zr0;  Az[o2 + 64 + l]  = (f16)zr1;
    Az[o2 + 128 + l] = (f16)zi0;  Az[o2 + 192 + l] = (f16)zi1;
    Au[o2 + l]       = (f16)(dr0*inv);  Au[o2 + 64 + l]  = (f16)(dr1*inv);
    Au[o2 + 128 + l] = (f16)(di0*inv);  Au[o2 + 192 + l] = (f16)(di1*inv);
}

// ---------------- prep M: folded constants + pack Bp[3][Mm][256] ----------------
__global__ void cpsf_prep_m(const float* __restrict__ zj_re, const float* __restrict__ zj_im,
                            const float* __restrict__ dj_re, const float* __restrict__ dj_im,
                            const float* __restrict__ alpha, const float* __restrict__ sp_,
                            const float* __restrict__ sq_, float* __restrict__ cm,
                            f16* __restrict__ Bp)
{
    const int m = blockIdx.x * 4 + (threadIdx.x >> 6);
    const int l = threadIdx.x & 63;
    const int o = m * Nn;
    float dr0 = dj_re[o + l], dr1 = dj_re[o + l + 64];
    float di0 = dj_im[o + l], di1 = dj_im[o + l + 64];
    float zr0 = zj_re[o + l], zr1 = zj_re[o + l + 64];
    float zi0 = zj_im[o + l], zi1 = zj_im[o + l + 64];
    float snd = dr0*dr0 + di0*di0 + dr1*dr1 + di1*di1;
    float sc1 = dr0*zr0 + di0*zi0 + dr1*zr1 + di1*zi1;
    float sc2 = dr0*zi0 - di0*zr0 + dr1*zi1 - di1*zr1;
    float sz2 = zr0*zr0 + zi0*zi0 + zr1*zr1 + zi1*zi1;
#pragma unroll
    for (int off = 1; off < 64; off <<= 1) {
        snd += __shfl_xor(snd, off);
        sc1 += __shfl_xor(sc1, off);
        sc2 += __shfl_xor(sc2, off);
        sz2 += __shfl_xor(sz2, off);
    }
    float nd = sqrtf(snd);
    nd = (nd == 0.0f) ? 1.0f : nd;
    float inv = 1.0f / nd;
    const size_t b0o = (size_t)m * 256;
    const size_t b1o = ((size_t)Mm + m) * 256;
    const size_t b2o = ((size_t)2 * Mm + m) * 256;
    Bp[b0o + l]       = (f16)(dr0*inv);  Bp[b0o + 64 + l]  = (f16)(dr1*inv);
    Bp[b0o + 128 + l] = (f16)(di0*inv);  Bp[b0o + 192 + l] = (f16)(di1*inv);
    Bp[b1o + l]       = (f16)(-di0*inv); Bp[b1o + 64 + l]  = (f16)(-di1*inv);
    Bp[b1o + 128 + l] = (f16)(dr0*inv);  Bp[b1o + 192 + l] = (f16)(dr1*inv);
    Bp[b2o + l]       = (f16)zr0;        Bp[b2o + 64 + l]  = (f16)zr1;
    Bp[b2o + 128 + l] = (f16)zi0;        Bp[b2o + 192 + l] = (f16)zi1;
    if (l == 0) {
        cm[1*Mm + m] = sc1 * inv;
        cm[2*Mm + m] = sc2 * inv;
        cm[3*Mm + m] = sz2;
        float sp = fmaxf(sp_[m], TINY_F);
        float sq = fmaxf(sq_[m], TINY_F);
        float sc = sqrtf(sp / PI_F);
        cm[4*Mm + m] = PI_F / sp;
        cm[5*Mm + m] = PI_F / sq;
        cm[6*Mm + m] = fmaxf(alpha[m], TINY_F) * sc * INV_SQRT_PI;
        cm[7*Mm + m] = sc;
    }
}

// ---------------- pack T transposed: Tt[s'=512][Mm] f16, s'=s*2+ri ----------------
__global__ void cpsf_pack_tt(const float* __restrict__ T_re, const float* __restrict__ T_im,
                             f16* __restrict__ Tt)
{
    __shared__ float tr[64][65], ti[64][65];
    const int mb = blockIdx.x * 64, sb = blockIdx.y * 64;
    const int tid = threadIdx.x;
    const int i0 = tid >> 6, j = tid & 63;
#pragma unroll
    for (int it = 0; it < 16; ++it) {
        int i = it * 4 + i0;
        tr[i][j] = T_re[(size_t)(mb + i) * Ss + sb + j];
        ti[i][j] = T_im[(size_t)(mb + i) * Ss + sb + j];
    }
    __syncthreads();
#pragma unroll
    for (int it = 0; it < 16; ++it) {
        int jj = it * 4 + i0;
        int sp = (sb + jj) * 2;
        Tt[(size_t)sp * Mm + mb + j]       = (f16)tr[j][jj];
        Tt[(size_t)(sp + 1) * Mm + mb + j] = (f16)ti[j][jj];
    }
}

// ---------------- MFMA kernel W: single-wave 32b x 32m tile, 5 maps, GH epilogue ----------------
// 64-thread block (1 wave), no barriers. mfma_f32_32x32x16_f16, K=256 in 16 chunks.
// LDS: 2 x 5KB dbuf (Az 512 | Au 512 | Bp0 512 | Bp1 512 | Bp2 512 f16 per buffer).
// Pipeline: issue chunk k+1's 5 loads, s_waitcnt vmcnt(5) -> chunk k ready; vmcnt(0) only at the end.
__global__ __launch_bounds__(64, 3) void cpsf_gemm_w(
    const f16* __restrict__ Az, const f16* __restrict__ Au,
    const f16* __restrict__ Bp, const float* __restrict__ cm,
    const float* __restrict__ z2v, f16* __restrict__ wbuf,
    float* __restrict__ den)
{
    __shared__ __align__(16) f16 sm[5120];   // 10 KB

    const int lane = threadIdx.x;
    const int mb0 = blockIdx.x * 32;
    const int bb0 = blockIdx.y * 32;

    // staging source per lane: row = lane>>1, 16B half = lane&1 (matches HW lane*16 dest)
    const int srow = lane >> 1;
    const int sh   = (lane & 1) * 8;                 // f16 units
    const f16* g0 = Az + (size_t)(bb0 + srow) * 256 + sh;
    const f16* g1 = Au + (size_t)(bb0 + srow) * 256 + sh;
    const f16* g2 = Bp + (size_t)(mb0 + srow) * 256 + sh;
    const f16* g3 = g2 + (size_t)Mm * 256;
    const f16* g4 = g3 + (size_t)Mm * 256;

    f32x16 aP0 = {}, aP1 = {}, aP2 = {}, aQ0 = {}, aQ1 = {};

    // each chunk consumes 16 f16 in K -> advance 16 f16 (32 B) per issue
#define ISSUE(buf) { \
    GLOAD16(g0, sm + (buf)*2560 +    0); g0 += 16; \
    GLOAD16(g1, sm + (buf)*2560 +  512); g1 += 16; \
    GLOAD16(g2, sm + (buf)*2560 + 1024); g2 += 16; \
    GLOAD16(g3, sm + (buf)*2560 + 1536); g3 += 16; \
    GLOAD16(g4, sm + (buf)*2560 + 2048); g4 += 16; }

    ISSUE(0)
    // A-frag layout (32x32x16): m = lane&31, k = (lane>>5)*8 + j ; chunk is [row][k16] row-major
    const int fo = (lane & 31) * 16 + (lane >> 5) * 8;   // f16 units
#pragma unroll
    for (int ks = 0; ks < 16; ++ks) {
        if (ks < 15) {
            ISSUE((ks + 1) & 1)
            __builtin_amdgcn_s_waitcnt(0x0F75);          // vmcnt(5): chunk ks complete
        } else {
            __builtin_amdgcn_s_waitcnt(0x0F70);          // vmcnt(0): final chunk
        }
        const f16* sb = sm + (ks & 1) * 2560;
        f16x8 az = *(const f16x8*)(sb + fo);
        f16x8 au = *(const f16x8*)(sb + 512 + fo);
        f16x8 b0 = *(const f16x8*)(sb + 1024 + fo);
        f16x8 b1 = *(const f16x8*)(sb + 1536 + fo);
        f16x8 b2 = *(const f16x8*)(sb + 2048 + fo);
        aP0 = __builtin_amdgcn_mfma_f32_32x32x16_f16(az, b0, aP0, 0, 0, 0);
        aP1 = __builtin_amdgcn_mfma_f32_32x32x16_f16(az, b1, aP1, 0, 0, 0);
        aP2 = __builtin_amdgcn_mfma_f32_32x32x16_f16(az, b2, aP2, 0, 0, 0);
        aQ0 = __builtin_amdgcn_mfma_f32_32x32x16_f16(au, b0, aQ0, 0, 0, 0);
        aQ1 = __builtin_amdgcn_mfma_f32_32x32x16_f16(au, b1, aQ1, 0, 0, 0);
    }
#undef ISSUE

    // ---------------- epilogue (fp32) ----------------
    // C layout (32x32): col(m) = lane&31 ; row(b) = (reg&3) + 8*(reg>>2) + 4*(lane>>5)
    const float GT[8] = {-2.9306374202572440f, -1.9816567566958429f,
                         -1.1571937124467802f, -0.3811869902073221f,
                          0.3811869902073221f,  1.1571937124467802f,
                          1.9816567566958429f,  2.9306374202572440f};
    const float GW[8] = {1.9960407221136762e-04f, 1.7077983007413475e-02f,
                         2.0780232581489188e-01f, 6.6114701255824129e-01f,
                         6.6114701255824129e-01f, 2.0780232581489188e-01f,
                         1.7077983007413475e-02f, 1.9960407221136762e-04f};

    const int m = mb0 + (lane & 31);
    const float c1  = cm[1*Mm + m], c2  = cm[2*Mm + m];
    const float zj2 = cm[3*Mm + m], isp = cm[4*Mm + m];
    const float isq = cm[5*Mm + m], cf  = cm[6*Mm + m];
    const float scl = cm[7*Mm + m];
    const int bhalf = 4 * (lane >> 5);

#pragma unroll
    for (int reg = 0; reg < 16; ++reg) {
        const int b = bb0 + (reg & 3) + 8 * (reg >> 2) + bhalf;
        const float z2b = z2v[b];
        float pr = aP0[reg] - c1;
        float pi = aP1[reg] - c2;
        float dz2 = z2b + zj2 - 2.0f * aP2[reg];
        float perp2 = fmaxf(dz2 - pr * pr - pi * pi, 0.0f);
        float base = -(isq * perp2 + isp * pi * pi);
        float rho = 0.0f;
#pragma unroll
        for (int k = 0; k < 8; ++k) {
            float dd = pr - scl * GT[k];
            rho = fmaf(GW[k], __expf(base - isp * dd * dd), rho);
        }
        float ar = aQ0[reg], ai = aQ1[reg];
        float wv = cf * (ar * ar + ai * ai) * rho;
        wbuf[(size_t)b * Mm + m] = (f16)(wv * WSC);
        // den: reduce across the 32 m-columns (lane bits 0..4)
        float v = wv;
        v += __shfl_xor(v, 1);
        v += __shfl_xor(v, 2);
        v += __shfl_xor(v, 4);
        v += __shfl_xor(v, 8);
        v += __shfl_xor(v, 16);
        if ((lane & 31) == 0) atomicAdd(den + b, v);
    }
}

// ---------------- MFMA kernel B: out_acc += w @ Tt^T ----------------
// Block 64b x 128s', 4 waves 2x2, wave tile 32b x 64s'. BK=64 (16 iters of K=1024).
__global__ __launch_bounds__(256, 4) void cpsf_gemm_out(
    const f16* __restrict__ wbuf, const f16* __restrict__ Tt,
    float* __restrict__ oacc)
{
    __shared__ __align__(16) f16 sm[1536 * 8];
    const int tid = threadIdx.x;
    const int wid = tid >> 6;
    const int lane = tid & 63;
    const int q = lane >> 4;
    const int li = lane & 15;
    const int sb0 = blockIdx.x * 128;
    const int bb0 = blockIdx.y * 64;
    const int kz0 = blockIdx.z * 1024;
    const int wb0 = (wid >> 1) * 32;
    const int ws0 = (wid & 1) * 64;

    const f16* gp[6];
    f16* lb[6];
#pragma unroll
    for (int i = 0; i < 6; ++i) {
        int c = i * 4 + wid;
        const f16* src;
        f16* dst;
        if (c < 8) {
            src = wbuf + (size_t)(bb0 + lane) * Mm + kz0 + c * 8;
            dst = sm + (size_t)c * 64 * 8;
        } else {
            int c2 = c - 8, g = c2 >> 1, rh = c2 & 1;
            src = Tt + (size_t)(sb0 + rh * 64 + lane) * Mm + kz0 + g * 8;
            dst = sm + (size_t)(512 + g * 128 + rh * 64) * 8;
        }
        gp[i] = src;
        lb[i] = dst;
    }

    f32x4 acc[2][4];
#pragma unroll
    for (int t = 0; t < 2; ++t)
#pragma unroll
        for (int u = 0; u < 4; ++u) acc[t][u] = (f32x4){0.f,0.f,0.f,0.f};

    for (int ks = 0; ks < 16; ++ks) {
        __syncthreads();
#pragma unroll
        for (int i = 0; i < 6; ++i) {
            GLOAD16(gp[i], lb[i]);
            gp[i] += 64;
        }
        __syncthreads();
#pragma unroll
        for (int j = 0; j < 2; ++j) {
            const int g = j * 4 + q;
            f16x8 af[2], bf[4];
#pragma unroll
            for (int t = 0; t < 2; ++t)
                af[t] = *(const f16x8*)(sm + (size_t)(g * 64 + wb0 + t * 16 + li) * 8);
#pragma unroll
            for (int u = 0; u < 4; ++u)
                bf[u] = *(const f16x8*)(sm + (size_t)(512 + g * 128 + ws0 + u * 16 + li) * 8);
#pragma unroll
            for (int t = 0; t < 2; ++t)
#pragma unroll
                for (int u = 0; u < 4; ++u)
                    acc[t][u] = __builtin_amdgcn_mfma_f32_16x16x32_f16(af[t], bf[u], acc[t][u], 0, 0, 0);
        }
    }
#pragma unroll
    for (int t = 0; t < 2; ++t)
#pragma unroll
        for (int u = 0; u < 4; ++u)
#pragma unroll
            for (int r = 0; r < 4; ++r)
                atomicAdd(oacc + (size_t)(bb0 + wb0 + t * 16 + q * 4 + r) * 512 + sb0 + ws0 + u * 16 + li,
                          acc[t][u][r]);
}

// ---------------- finalize ----------------
__global__ void cpsf_fin(const float* __restrict__ oacc, const float* __restrict__ den,
                         float* __restrict__ out)
{
    int i = blockIdx.x * 256 + threadIdx.x;
    float d = (den[i >> 9] + EPS_TOTAL) * WSC;
    out[i] = oacc[i] / d;
}

extern "C" void kernel_launch(void* const* d_in, const int* in_sizes, int n_in,
                              void* d_out, int out_size, void* d_ws, size_t ws_size,
                              hipStream_t stream)
{
    (void)in_sizes; (void)n_in; (void)out_size; (void)ws_size;
    const float* z_re  = (const float*)d_in[0];
    const float* z_im  = (const float*)d_in[1];
    const float* d_re  = (const float*)d_in[2];
    const float* d_im  = (const float*)d_in[3];
    const float* zj_re = (const float*)d_in[4];
    const float* zj_im = (const float*)d_in[5];
    const float* dj_re = (const float*)d_in[6];
    const float* dj_im = (const float*)d_in[7];
    const float* T_re  = (const float*)d_in[8];
    const float* T_im  = (const float*)d_in[9];
    const float* alpha = (const float*)d_in[10];
    const float* s_par = (const float*)d_in[11];
    const float* s_perp= (const float*)d_in[12];

    // workspace layout (bytes); total ~41.1 MB
    char* w8 = (char*)d_ws;
    const size_t o_out = 0;
    const size_t o_den = o_out + (size_t)Bq * 512 * 4;   // 2 MB
    const size_t o_z2  = o_den + 4096;
    const size_t o_cm  = o_z2 + 4096;
    const size_t o_az  = o_cm + (size_t)8 * Mm * 4;      // 256 KB
    const size_t o_au  = o_az + (size_t)Bq * 256 * 2;
    const size_t o_bp  = o_au + (size_t)Bq * 256 * 2;
    const size_t o_tt  = o_bp + (size_t)3 * Mm * 256 * 2;   // 12.6 MB
    const size_t o_wb  = o_tt + (size_t)512 * Mm * 2;       // 8.4 MB

    float* oacc = (float*)(w8 + o_out);
    float* den  = (float*)(w8 + o_den);
    float* z2   = (float*)(w8 + o_z2);
    float* cm   = (float*)(w8 + o_cm);
    f16*   Az   = (f16*)(w8 + o_az);
    f16*   Au   = (f16*)(w8 + o_au);
    f16*   Bp   = (f16*)(w8 + o_bp);
    f16*   Tt   = (f16*)(w8 + o_tt);
    f16*   wb   = (f16*)(w8 + o_wb);

    (void)hipMemsetAsync(d_ws, 0, o_cm, stream);   // zero out_acc + den

    cpsf_prep_a<<<Bq / 4, 256, 0, stream>>>(z_re, z_im, d_re, d_im, z2, Az, Au);
    cpsf_prep_m<<<Mm / 4, 256, 0, stream>>>(zj_re, zj_im, dj_re, dj_im,
                                            alpha, s_par, s_perp, cm, Bp);
    cpsf_pack_tt<<<dim3(Mm / 64, Ss / 64), 256, 0, stream>>>(T_re, T_im, Tt);
    cpsf_gemm_w<<<dim3(Mm / 32, Bq / 32), 64, 0, stream>>>(Az, Au, Bp, cm, z2, wb, den);
    cpsf_gemm_out<<<dim3(4, Bq / 64, Mm / 1024), 256, 0, stream>>>(wb, Tt, oacc);
    cpsf_fin<<<(Bq * 512) / 256, 256, 0, stream>>>(oacc, den, (float*)d_out);
}